// Round 1
// 436.561 us; speedup vs baseline: 1.0015x; 1.0015x over previous
//
#include <hip/hip_runtime.h>
#include <hip/hip_bf16.h>
#include <math.h>

// Problem constants
#define BS 32
#define TT 512
#define HH 1024
#define NH 16
#define DH 64
#define MM (BS*TT)          // 16384 rows
#define NCAT 2176           // 1024(Q) + 1024(K) + 64(V) + 64(pad)

typedef __attribute__((ext_vector_type(8))) __bf16 bf16x8;
typedef __attribute__((ext_vector_type(4))) float  f32x4;

#define QSCALE 0.18033688011112042f   // dh^-0.5 * log2(e) -> softmax in exp2 domain

// async global->LDS, 16B per lane, LDS dest = wave-uniform base + lane*16
__device__ __forceinline__ void gld16(const void* g, void* l) {
    __builtin_amdgcn_global_load_lds(
        (const __attribute__((address_space(1))) unsigned int*)g,
        (__attribute__((address_space(3))) unsigned int*)l,
        16, 0, 0);
}

// ---------------------------------------------------------------------------
// Prep 1: x fp32 -> bf16 (row-major [M][K] unchanged)
// ---------------------------------------------------------------------------
__global__ __launch_bounds__(256) void cvt_x(const float* __restrict__ x,
                                             __bf16* __restrict__ xb)
{
    const size_t i = ((size_t)blockIdx.x * 256 + threadIdx.x) * 8;
    float4 a = *(const float4*)(x + i);
    float4 b = *(const float4*)(x + i + 4);
    bf16x8 v;
    v[0] = (__bf16)a.x; v[1] = (__bf16)a.y; v[2] = (__bf16)a.z; v[3] = (__bf16)a.w;
    v[4] = (__bf16)b.x; v[5] = (__bf16)b.y; v[6] = (__bf16)b.z; v[7] = (__bf16)b.w;
    *(bf16x8*)(xb + i) = v;
}

// ---------------------------------------------------------------------------
// Prep 2: Wt[n][k] bf16 = concat(Wq,Wk,Wv,0)^T; bias_cat[n] fp32.
// ---------------------------------------------------------------------------
__global__ __launch_bounds__(256) void prep_w(
    const float* __restrict__ Wq, const float* __restrict__ Wk,
    const float* __restrict__ Wv, const float* __restrict__ bq_,
    const float* __restrict__ bk_, const float* __restrict__ bv_,
    __bf16* __restrict__ Wt, float* __restrict__ bias_cat)
{
    __shared__ __align__(16) __bf16 tile[64][72];
    const int tid = threadIdx.x;
    const int n0 = blockIdx.x * 64;
    const int k0 = blockIdx.y * 64;

    const int n_l = tid & 63;
    const int k_b = tid >> 6;
    const int n   = n0 + n_l;
    #pragma unroll
    for (int j = 0; j < 16; ++j) {
        const int k_l = j * 4 + k_b;
        const int k   = k0 + k_l;
        float v;
        if (n < 1024)      v = Wq[(size_t)k * 1024 + n];
        else if (n < 2048) v = Wk[(size_t)k * 1024 + (n - 1024)];
        else if (n < 2112) v = Wv[(size_t)k * 64 + (n - 2048)];
        else               v = 0.f;
        tile[n_l][k_l] = (__bf16)v;
    }
    if (blockIdx.y == 0 && tid < 64) {
        const int nn = n0 + tid;
        bias_cat[nn] = (nn < 1024) ? bq_[nn]
                     : (nn < 2048) ? bk_[nn - 1024]
                     : (nn < 2112) ? bv_[nn - 2048] : 0.f;
    }
    __syncthreads();
    const int n_l2 = tid >> 2;
    const int k_l2 = (tid & 3) * 16;
    __bf16* dst = Wt + (size_t)(n0 + n_l2) * 1024 + k0 + k_l2;
    *(bf16x8*)dst       = *(const bf16x8*)&tile[n_l2][k_l2];
    *(bf16x8*)(dst + 8) = *(const bf16x8*)&tile[n_l2][k_l2 + 8];
}

// ---------------------------------------------------------------------------
// Fused QKV GEMM, m97 structure: 128x128 tile, BK=32, global_load_lds w=16.
// ---------------------------------------------------------------------------
__global__ __launch_bounds__(256) void gemm_qkv(
    const __bf16* __restrict__ A, const __bf16* __restrict__ B,
    const float* __restrict__ bias_cat,
    __bf16* __restrict__ Qo, __bf16* __restrict__ Ko,
    __bf16* __restrict__ Vt)
{
    __shared__ __align__(16) __bf16 sA[128 * 32];
    __shared__ __align__(16) __bf16 sB[128 * 32];

    const int tid  = threadIdx.x;
    const int wv   = tid >> 6;
    const int ln   = tid & 63;
    const int quad = ln >> 4;
    const int l16  = ln & 15;
    const int m0 = blockIdx.y * 128;
    const int n0 = blockIdx.x * 128;

    const int rw = (wv & 1) * 64;    // wave row quadrant
    const int cw = (wv >> 1) * 64;   // wave col quadrant

    f32x4 acc[4][4];
    #pragma unroll
    for (int i = 0; i < 4; ++i)
        #pragma unroll
        for (int j = 0; j < 4; ++j) acc[i][j] = f32x4{0, 0, 0, 0};

    const int srow = wv * 16 + (ln >> 2);
    const int scol = (ln & 3) * 8;
    const __bf16* ga0 = A + (size_t)(m0 + srow) * 1024 + scol;
    const __bf16* gb0 = B + (size_t)(n0 + srow) * 1024 + scol;
    __bf16* la0 = sA + wv * 512;
    __bf16* lb0 = sB + wv * 512;

    for (int k0 = 0; k0 < 1024; k0 += 32) {
        gld16(ga0 + k0, la0);
        gld16(ga0 + (size_t)64 * 1024 + k0, la0 + 2048);
        gld16(gb0 + k0, lb0);
        gld16(gb0 + (size_t)64 * 1024 + k0, lb0 + 2048);
        __syncthreads();

        bf16x8 af[4], bfr[4];
        #pragma unroll
        for (int mt = 0; mt < 4; ++mt)
            af[mt] = *(const bf16x8*)&sA[(rw + mt * 16 + l16) * 32 + quad * 8];
        #pragma unroll
        for (int nt = 0; nt < 4; ++nt)
            bfr[nt] = *(const bf16x8*)&sB[(cw + nt * 16 + l16) * 32 + quad * 8];
        #pragma unroll
        for (int mt = 0; mt < 4; ++mt)
            #pragma unroll
            for (int nt = 0; nt < 4; ++nt)
                acc[mt][nt] = __builtin_amdgcn_mfma_f32_16x16x32_bf16(af[mt], bfr[nt], acc[mt][nt], 0, 0, 0);
        __syncthreads();
    }

    #pragma unroll
    for (int mt = 0; mt < 4; ++mt) {
        #pragma unroll
        for (int nt = 0; nt < 4; ++nt) {
            const int colb = n0 + cw + nt * 16 + l16;
            if (colb >= 2112) continue;
            const float bias = bias_cat[colb];
            #pragma unroll
            for (int r = 0; r < 4; ++r) {
                const int row = m0 + rw + mt * 16 + quad * 4 + r;
                const int b = row >> 9, t = row & 511;
                float v = acc[mt][nt][r] + bias;
                if (colb < 1024) {
                    const int h = colb >> 6, d = colb & 63;
                    Qo[(((size_t)(b * NH + h) * TT) + t) * DH + d] = (__bf16)(v * QSCALE);
                } else if (colb < 2048) {
                    const int c = colb - 1024;
                    const int h = c >> 6, d = c & 63;
                    Ko[(((size_t)(b * NH + h) * TT) + t) * DH + d] = (__bf16)v;
                } else {
                    const int d = colb - 2048;
                    Vt[((size_t)(b * DH + d)) * TT + t] = (__bf16)v;
                }
            }
        }
    }
}

// ---------------------------------------------------------------------------
// MFMA flash attention, NO online max (scores bounded in exp2 domain).
// v2 restructure:
//   * block = 1024 threads = 16 waves = the 16 heads of one (b, pair).
//   * each wave processes TWO 32-query tiles sequentially: qt2 = pair and
//     qt2 = 15-pair  ->  every wave does exactly (pair+1)+(16-pair) = 17
//     k-block iterations: perfect load balance, no causal straggler tail.
//   * head-mean accumulated via LDS atomics (on-CU), ONE plain float4 store
//     per mav element per block. Eliminates 16.7M global fp32 atomics
//     (64 MB of HBM atomic write traffic + fabric contention) and the
//     zero_mav kernel.
// Grid = BS*8 = 256 blocks = exactly 1 block/CU, uniform work.
// ---------------------------------------------------------------------------
__global__ __launch_bounds__(1024) void attn_mfma(
    const __bf16* __restrict__ Q, const __bf16* __restrict__ K,
    const __bf16* __restrict__ Vt, float* __restrict__ attn_vec,
    float* __restrict__ mav)
{
    __shared__ float smav[64][65];   // rows 0..31: tile qt2=pair, 32..63: qt2=15-pair; +1 pad breaks 4-way quad conflict

    const int wave = threadIdx.x >> 6;     // = head
    const int lane = threadIdx.x & 63;
    const int pair = blockIdx.x & 7;
    const int b    = blockIdx.x >> 3;
    const int bh   = b * NH + wave;
    const int quad = lane >> 4;
    const int l16  = lane & 15;

    // zero the LDS head-mean accumulator
    {
        float* p = &smav[0][0];
        for (int i = threadIdx.x; i < 64 * 65; i += 1024) p[i] = 0.f;
    }
    __syncthreads();

    const __bf16* Qbh = Q  + (size_t)bh * TT * DH;
    const __bf16* Kbh = K  + (size_t)bh * TT * DH;
    const __bf16* Vb  = Vt + (size_t)b  * DH * TT;

    // permuted K row: sigma1(l16) = (l16>>2)*8 + (l16&3); sigma2 = +4
    const int perm = ((l16 >> 2) << 3) + (l16 & 3);
    const __bf16* kp1 = Kbh + (size_t)perm * DH;
    const __bf16* kp2 = Kbh + (size_t)(perm + 4) * DH;

    #pragma unroll 1
    for (int rep = 0; rep < 2; ++rep) {
        const int qt2 = rep ? (15 - pair) : pair;
        const int q0  = qt2 << 5;
        const int kend = q0 + 32;

        const bf16x8 qA_lo = *(const bf16x8*)(Qbh + (size_t)(q0 + l16) * DH + quad * 8);
        const bf16x8 qA_hi = *(const bf16x8*)(Qbh + (size_t)(q0 + l16) * DH + 32 + quad * 8);
        const bf16x8 qB_lo = *(const bf16x8*)(Qbh + (size_t)(q0 + 16 + l16) * DH + quad * 8);
        const bf16x8 qB_hi = *(const bf16x8*)(Qbh + (size_t)(q0 + 16 + l16) * DH + 32 + quad * 8);

        f32x4 OA[4] = {f32x4{0,0,0,0}, f32x4{0,0,0,0}, f32x4{0,0,0,0}, f32x4{0,0,0,0}};
        f32x4 OB[4] = {f32x4{0,0,0,0}, f32x4{0,0,0,0}, f32x4{0,0,0,0}, f32x4{0,0,0,0}};
        float lA = 0.f, lB = 0.f;     // per-lane partial denominators

        bf16x8 k1a = *(const bf16x8*)(kp1 + quad * 8);
        bf16x8 k1b = *(const bf16x8*)(kp1 + 32 + quad * 8);
        bf16x8 k2a = *(const bf16x8*)(kp2 + quad * 8);
        bf16x8 k2b = *(const bf16x8*)(kp2 + 32 + quad * 8);

        for (int kb0 = 0; kb0 < kend; kb0 += 32) {
            const __bf16* vp = Vb + (size_t)l16 * TT + kb0 + quad * 8;
            bf16x8 vf0 = *(const bf16x8*)(vp);
            bf16x8 vf1 = *(const bf16x8*)(vp + (size_t)16 * TT);
            bf16x8 vf2 = *(const bf16x8*)(vp + (size_t)32 * TT);
            bf16x8 vf3 = *(const bf16x8*)(vp + (size_t)48 * TT);

            f32x4 s1A = __builtin_amdgcn_mfma_f32_16x16x32_bf16(k1a, qA_lo, f32x4{0,0,0,0}, 0, 0, 0);
            s1A       = __builtin_amdgcn_mfma_f32_16x16x32_bf16(k1b, qA_hi, s1A, 0, 0, 0);
            f32x4 s2A = __builtin_amdgcn_mfma_f32_16x16x32_bf16(k2a, qA_lo, f32x4{0,0,0,0}, 0, 0, 0);
            s2A       = __builtin_amdgcn_mfma_f32_16x16x32_bf16(k2b, qA_hi, s2A, 0, 0, 0);
            f32x4 s1B = __builtin_amdgcn_mfma_f32_16x16x32_bf16(k1a, qB_lo, f32x4{0,0,0,0}, 0, 0, 0);
            s1B       = __builtin_amdgcn_mfma_f32_16x16x32_bf16(k1b, qB_hi, s1B, 0, 0, 0);
            f32x4 s2B = __builtin_amdgcn_mfma_f32_16x16x32_bf16(k2a, qB_lo, f32x4{0,0,0,0}, 0, 0, 0);
            s2B       = __builtin_amdgcn_mfma_f32_16x16x32_bf16(k2b, qB_hi, s2B, 0, 0, 0);

            // prefetch next K block (clamped; overlaps exp+PV)
            {
                const int kbn = (kb0 + 32 < kend) ? kb0 + 32 : kb0;
                const __bf16* nk1 = kp1 + (size_t)kbn * DH;
                const __bf16* nk2 = kp2 + (size_t)kbn * DH;
                k1a = *(const bf16x8*)(nk1 + quad * 8);
                k1b = *(const bf16x8*)(nk1 + 32 + quad * 8);
                k2a = *(const bf16x8*)(nk2 + quad * 8);
                k2b = *(const bf16x8*)(nk2 + 32 + quad * 8);
            }

            if (kb0 == q0) {   // only the diagonal block needs masking
                const int qqA = q0 + l16, qqB = q0 + 16 + l16;
                #pragma unroll
                for (int r = 0; r < 4; ++r) {
                    const int key1 = kb0 + quad * 8 + r;
                    const int key2 = key1 + 4;
                    if (key1 > qqA) s1A[r] = -INFINITY;
                    if (key2 > qqA) s2A[r] = -INFINITY;
                    if (key1 > qqB) s1B[r] = -INFINITY;
                    if (key2 > qqB) s2B[r] = -INFINITY;
                }
            }

            // p = exp2(s); accumulate per-lane denominator; no rescale, no shuffles
            bf16x8 pfA, pfB;
            float psA = 0.f, psB = 0.f;
            #pragma unroll
            for (int r = 0; r < 4; ++r) {
                float pa0 = exp2f(s1A[r]);
                float pa1 = exp2f(s2A[r]);
                float pb0 = exp2f(s1B[r]);
                float pb1 = exp2f(s2B[r]);
                psA += pa0 + pa1;
                psB += pb0 + pb1;
                pfA[r]     = (__bf16)pa0;
                pfA[4 + r] = (__bf16)pa1;
                pfB[r]     = (__bf16)pb0;
                pfB[4 + r] = (__bf16)pb1;
            }
            lA += psA;
            lB += psB;

            OA[0] = __builtin_amdgcn_mfma_f32_16x16x32_bf16(pfA, vf0, OA[0], 0, 0, 0);
            OB[0] = __builtin_amdgcn_mfma_f32_16x16x32_bf16(pfB, vf0, OB[0], 0, 0, 0);
            OA[1] = __builtin_amdgcn_mfma_f32_16x16x32_bf16(pfA, vf1, OA[1], 0, 0, 0);
            OB[1] = __builtin_amdgcn_mfma_f32_16x16x32_bf16(pfB, vf1, OB[1], 0, 0, 0);
            OA[2] = __builtin_amdgcn_mfma_f32_16x16x32_bf16(pfA, vf2, OA[2], 0, 0, 0);
            OB[2] = __builtin_amdgcn_mfma_f32_16x16x32_bf16(pfB, vf2, OB[2], 0, 0, 0);
            OA[3] = __builtin_amdgcn_mfma_f32_16x16x32_bf16(pfA, vf3, OA[3], 0, 0, 0);
            OB[3] = __builtin_amdgcn_mfma_f32_16x16x32_bf16(pfB, vf3, OB[3], 0, 0, 0);
        }

        // reduce denominators across quads (each lane then holds the full sum
        // for query l16 (A) / 16+l16 (B))
        lA += __shfl_xor(lA, 16);
        lA += __shfl_xor(lA, 32);
        lB += __shfl_xor(lB, 16);
        lB += __shfl_xor(lB, 32);

        #pragma unroll
        for (int r = 0; r < 4; ++r) {
            const float invA = 1.0f / __shfl(lA, quad * 4 + r);
            const float invB = 1.0f / __shfl(lB, quad * 4 + r);
            const int tA = q0 + quad * 4 + r;
            const int tB = tA + 16;
            const int ltA = rep * 32 + quad * 4 + r;   // LDS row (tile-local + rep offset)
            const int ltB = ltA + 16;
            float* opA = attn_vec + ((size_t)bh * TT + tA) * DH + l16;
            float* opB = attn_vec + ((size_t)bh * TT + tB) * DH + l16;
            #pragma unroll
            for (int nt = 0; nt < 4; ++nt) {
                const float vA = OA[nt][r] * invA;
                const float vB = OB[nt][r] * invB;
                opA[nt * 16] = vA;
                opB[nt * 16] = vB;
                atomicAdd(&smav[ltA][nt * 16 + l16], vA * (1.f / 16.f));
                atomicAdd(&smav[ltB][nt * 16 + l16], vB * (1.f / 16.f));
            }
        }
    }

    __syncthreads();

    // block-cooperative plain store of the head-mean (each element written once)
    {
        const int row = threadIdx.x >> 4;          // 0..63
        const int d0  = (threadIdx.x & 15) * 4;
        const int t   = (row < 32) ? ((pair << 5) + row)
                                   : (((15 - pair) << 5) + (row - 32));
        float4 v;
        v.x = smav[row][d0];
        v.y = smav[row][d0 + 1];
        v.z = smav[row][d0 + 2];
        v.w = smav[row][d0 + 3];
        *(float4*)(mav + ((size_t)(b * TT + t)) * DH + d0) = v;
    }
}

// ---------------------------------------------------------------------------
// Out-proj GEMM (64x64 tile, fp32 A): out[M,1024] = mav[M,64] @ Wo[64,1024]
// ---------------------------------------------------------------------------
__global__ __launch_bounds__(256) void gemm_out(
    const float* __restrict__ A, const float* __restrict__ B,
    float* __restrict__ C, int M, int N, int K)
{
    __shared__ __align__(16) __bf16 sA[64][32];
    __shared__ __align__(16) __bf16 sB[64][32];

    const int tid  = threadIdx.x;
    const int wave = tid >> 6;
    const int lane = tid & 63;
    const int m0 = blockIdx.y * 64;
    const int n0 = blockIdx.x * 64;

    f32x4 acc[4] = {f32x4{0,0,0,0}, f32x4{0,0,0,0}, f32x4{0,0,0,0}, f32x4{0,0,0,0}};

    const int ar = tid >> 2;
    const int ac = (tid & 3) * 8;
    const int bk = tid >> 3;
    const int bc = (tid & 7) * 8;
    const int quad = lane >> 4;
    const int l16  = lane & 15;

    for (int k0 = 0; k0 < K; k0 += 32) {
        const float* ap = A + (size_t)(m0 + ar) * K + k0 + ac;
        float4 a0 = *(const float4*)ap;
        float4 a1 = *(const float4*)(ap + 4);
        {
            bf16x8 av;
            av[0] = (__bf16)a0.x; av[1] = (__bf16)a0.y; av[2] = (__bf16)a0.z; av[3] = (__bf16)a0.w;
            av[4] = (__bf16)a1.x; av[5] = (__bf16)a1.y; av[6] = (__bf16)a1.z; av[7] = (__bf16)a1.w;
            *(bf16x8*)&sA[ar][ac] = av;
        }
        const float* bp = B + (size_t)(k0 + bk) * N + n0 + bc;
        float4 b0 = *(const float4*)bp;
        float4 b1 = *(const float4*)(bp + 4);
        sB[bc + 0][bk] = (__bf16)b0.x;
        sB[bc + 1][bk] = (__bf16)b0.y;
        sB[bc + 2][bk] = (__bf16)b0.z;
        sB[bc + 3][bk] = (__bf16)b0.w;
        sB[bc + 4][bk] = (__bf16)b1.x;
        sB[bc + 5][bk] = (__bf16)b1.y;
        sB[bc + 6][bk] = (__bf16)b1.z;
        sB[bc + 7][bk] = (__bf16)b1.w;
        __syncthreads();

        bf16x8 afrag = *(const bf16x8*)&sA[wave * 16 + l16][quad * 8];
        #pragma unroll
        for (int tn = 0; tn < 4; ++tn) {
            bf16x8 bfrag = *(const bf16x8*)&sB[tn * 16 + l16][quad * 8];
            acc[tn] = __builtin_amdgcn_mfma_f32_16x16x32_bf16(afrag, bfrag, acc[tn], 0, 0, 0);
        }
        __syncthreads();
    }

    #pragma unroll
    for (int tn = 0; tn < 4; ++tn) {
        #pragma unroll
        for (int r = 0; r < 4; ++r) {
            int row = m0 + wave * 16 + quad * 4 + r;
            int col = n0 + tn * 16 + l16;
            C[(size_t)row * N + col] = acc[tn][r];
        }
    }
}

// ---------------------------------------------------------------------------
extern "C" void kernel_launch(void* const* d_in, const int* in_sizes, int n_in,
                              void* d_out, int out_size, void* d_ws, size_t ws_size,
                              hipStream_t stream)
{
    const float* x  = (const float*)d_in[0];
    const float* Wq = (const float*)d_in[1];
    const float* bq = (const float*)d_in[2];
    const float* Wk = (const float*)d_in[3];
    const float* bk = (const float*)d_in[4];
    const float* Wv = (const float*)d_in[5];
    const float* bv = (const float*)d_in[6];
    const float* Wo = (const float*)d_in[7];

    float* out      = (float*)d_out;                       // [32,512,1024]
    float* attn_vec = out + (size_t)MM * HH;               // [32,16,512,64]

    char* ws = (char*)d_ws;
    __bf16* xb  = (__bf16*)ws;                              // [M][1024]    33.5 MB
    __bf16* Wt  = xb + (size_t)MM * HH;                     // [2176][1024]  4.45 MB
    float* bias_cat = (float*)(Wt + (size_t)NCAT * HH);     // 2176 (pad 2304)
    __bf16* Qb  = (__bf16*)(bias_cat + 2304);               // [b,h,t,d]    33.5 MB
    __bf16* Kb  = Qb + (size_t)MM * HH;                     // [b,h,t,d]    33.5 MB
    __bf16* Vt  = Kb + (size_t)MM * HH;                     // [b,d,t]       2.1 MB
    float*  mav = (float*)xb;   // alias: xb dead after gemm_qkv; fully overwritten by attn

    cvt_x<<<MM * HH / (256 * 8), 256, 0, stream>>>(x, xb);
    prep_w<<<dim3(NCAT / 64, HH / 64), 256, 0, stream>>>(Wq, Wk, Wv, bq, bk, bv, Wt, bias_cat);
    gemm_qkv<<<dim3(NCAT / 128, MM / 128), 256, 0, stream>>>(xb, Wt, bias_cat, Qb, Kb, Vt);
    attn_mfma<<<BS * 8, 1024, 0, stream>>>(Qb, Kb, Vt, attn_vec, mav);
    gemm_out<<<dim3(HH / 64, MM / 64), 256, 0, stream>>>(mav, Wo, out, MM, HH, DH);
}

// Round 2
// 427.457 us; speedup vs baseline: 1.0228x; 1.0213x over previous
//
#include <hip/hip_runtime.h>
#include <hip/hip_bf16.h>
#include <math.h>

// Problem constants
#define BS 32
#define TT 512
#define HH 1024
#define NH 16
#define DH 64
#define MM (BS*TT)          // 16384 rows
#define NCAT 2176           // 1024(Q) + 1024(K) + 64(V) + 64(pad)

typedef __attribute__((ext_vector_type(8))) __bf16 bf16x8;
typedef __attribute__((ext_vector_type(4))) float  f32x4;

#define QSCALE 0.18033688011112042f   // dh^-0.5 * log2(e) -> softmax in exp2 domain

// async global->LDS, 16B per lane, LDS dest = wave-uniform base + lane*16
__device__ __forceinline__ void gld16(const void* g, void* l) {
    __builtin_amdgcn_global_load_lds(
        (const __attribute__((address_space(1))) unsigned int*)g,
        (__attribute__((address_space(3))) unsigned int*)l,
        16, 0, 0);
}

// ---------------------------------------------------------------------------
// Prep 1: x fp32 -> bf16 (row-major [M][K] unchanged)
// ---------------------------------------------------------------------------
__global__ __launch_bounds__(256) void cvt_x(const float* __restrict__ x,
                                             __bf16* __restrict__ xb)
{
    const size_t i = ((size_t)blockIdx.x * 256 + threadIdx.x) * 8;
    float4 a = *(const float4*)(x + i);
    float4 b = *(const float4*)(x + i + 4);
    bf16x8 v;
    v[0] = (__bf16)a.x; v[1] = (__bf16)a.y; v[2] = (__bf16)a.z; v[3] = (__bf16)a.w;
    v[4] = (__bf16)b.x; v[5] = (__bf16)b.y; v[6] = (__bf16)b.z; v[7] = (__bf16)b.w;
    *(bf16x8*)(xb + i) = v;
}

// ---------------------------------------------------------------------------
// Prep 2: Wt[n][k] bf16 = concat(Wq,Wk,Wv,0)^T; bias_cat[n] fp32.
// ---------------------------------------------------------------------------
__global__ __launch_bounds__(256) void prep_w(
    const float* __restrict__ Wq, const float* __restrict__ Wk,
    const float* __restrict__ Wv, const float* __restrict__ bq_,
    const float* __restrict__ bk_, const float* __restrict__ bv_,
    __bf16* __restrict__ Wt, float* __restrict__ bias_cat)
{
    __shared__ __align__(16) __bf16 tile[64][72];
    const int tid = threadIdx.x;
    const int n0 = blockIdx.x * 64;
    const int k0 = blockIdx.y * 64;

    const int n_l = tid & 63;
    const int k_b = tid >> 6;
    const int n   = n0 + n_l;
    #pragma unroll
    for (int j = 0; j < 16; ++j) {
        const int k_l = j * 4 + k_b;
        const int k   = k0 + k_l;
        float v;
        if (n < 1024)      v = Wq[(size_t)k * 1024 + n];
        else if (n < 2048) v = Wk[(size_t)k * 1024 + (n - 1024)];
        else if (n < 2112) v = Wv[(size_t)k * 64 + (n - 2048)];
        else               v = 0.f;
        tile[n_l][k_l] = (__bf16)v;
    }
    if (blockIdx.y == 0 && tid < 64) {
        const int nn = n0 + tid;
        bias_cat[nn] = (nn < 1024) ? bq_[nn]
                     : (nn < 2048) ? bk_[nn - 1024]
                     : (nn < 2112) ? bv_[nn - 2048] : 0.f;
    }
    __syncthreads();
    const int n_l2 = tid >> 2;
    const int k_l2 = (tid & 3) * 16;
    __bf16* dst = Wt + (size_t)(n0 + n_l2) * 1024 + k0 + k_l2;
    *(bf16x8*)dst       = *(const bf16x8*)&tile[n_l2][k_l2];
    *(bf16x8*)(dst + 8) = *(const bf16x8*)&tile[n_l2][k_l2 + 8];
}

// ---------------------------------------------------------------------------
// Fused QKV GEMM, m97 structure: 128x128 tile, BK=32, global_load_lds w=16.
// v3: bijective XCD-aware block swizzle (nwg=2176=8*272) for L2 locality.
// ---------------------------------------------------------------------------
__global__ __launch_bounds__(256) void gemm_qkv(
    const __bf16* __restrict__ A, const __bf16* __restrict__ B,
    const float* __restrict__ bias_cat,
    __bf16* __restrict__ Qo, __bf16* __restrict__ Ko,
    __bf16* __restrict__ Vt)
{
    __shared__ __align__(16) __bf16 sA[128 * 32];
    __shared__ __align__(16) __bf16 sB[128 * 32];

    const int tid  = threadIdx.x;
    const int wv   = tid >> 6;
    const int ln   = tid & 63;
    const int quad = ln >> 4;
    const int l16  = ln & 15;

    // XCD swizzle: grid = dim3(17,128) -> 2176 blocks, 2176 % 8 == 0
    const int orig = blockIdx.y * 17 + blockIdx.x;
    const int swz  = (orig & 7) * 272 + (orig >> 3);
    const int m0 = (swz / 17) * 128;
    const int n0 = (swz % 17) * 128;

    const int rw = (wv & 1) * 64;    // wave row quadrant
    const int cw = (wv >> 1) * 64;   // wave col quadrant

    f32x4 acc[4][4];
    #pragma unroll
    for (int i = 0; i < 4; ++i)
        #pragma unroll
        for (int j = 0; j < 4; ++j) acc[i][j] = f32x4{0, 0, 0, 0};

    const int srow = wv * 16 + (ln >> 2);
    const int scol = (ln & 3) * 8;
    const __bf16* ga0 = A + (size_t)(m0 + srow) * 1024 + scol;
    const __bf16* gb0 = B + (size_t)(n0 + srow) * 1024 + scol;
    __bf16* la0 = sA + wv * 512;
    __bf16* lb0 = sB + wv * 512;

    for (int k0 = 0; k0 < 1024; k0 += 32) {
        gld16(ga0 + k0, la0);
        gld16(ga0 + (size_t)64 * 1024 + k0, la0 + 2048);
        gld16(gb0 + k0, lb0);
        gld16(gb0 + (size_t)64 * 1024 + k0, lb0 + 2048);
        __syncthreads();

        bf16x8 af[4], bfr[4];
        #pragma unroll
        for (int mt = 0; mt < 4; ++mt)
            af[mt] = *(const bf16x8*)&sA[(rw + mt * 16 + l16) * 32 + quad * 8];
        #pragma unroll
        for (int nt = 0; nt < 4; ++nt)
            bfr[nt] = *(const bf16x8*)&sB[(cw + nt * 16 + l16) * 32 + quad * 8];
        #pragma unroll
        for (int mt = 0; mt < 4; ++mt)
            #pragma unroll
            for (int nt = 0; nt < 4; ++nt)
                acc[mt][nt] = __builtin_amdgcn_mfma_f32_16x16x32_bf16(af[mt], bfr[nt], acc[mt][nt], 0, 0, 0);
        __syncthreads();
    }

    #pragma unroll
    for (int mt = 0; mt < 4; ++mt) {
        #pragma unroll
        for (int nt = 0; nt < 4; ++nt) {
            const int colb = n0 + cw + nt * 16 + l16;
            if (colb >= 2112) continue;
            const float bias = bias_cat[colb];
            #pragma unroll
            for (int r = 0; r < 4; ++r) {
                const int row = m0 + rw + mt * 16 + quad * 4 + r;
                const int b = row >> 9, t = row & 511;
                float v = acc[mt][nt][r] + bias;
                if (colb < 1024) {
                    const int h = colb >> 6, d = colb & 63;
                    Qo[(((size_t)(b * NH + h) * TT) + t) * DH + d] = (__bf16)(v * QSCALE);
                } else if (colb < 2048) {
                    const int c = colb - 1024;
                    const int h = c >> 6, d = c & 63;
                    Ko[(((size_t)(b * NH + h) * TT) + t) * DH + d] = (__bf16)v;
                } else {
                    const int d = colb - 2048;
                    Vt[((size_t)(b * DH + d)) * TT + t] = (__bf16)v;
                }
            }
        }
    }
}

// ---------------------------------------------------------------------------
// MFMA flash attention.
// v3: V (shared across the block's 16 heads) staged ONCE into LDS
//     (64x512 bf16, row pitch 520 -> conflict-free ds_read_b128), removing
//     ~280 MB of logical / ~140 MB of HBM V re-reads and the 900-cyc V-miss
//     from the inner-loop critical path. K register pipeline deepened to 2
//     (cur/next) so K HBM latency gets a full iteration of cover.
// Block = 1024 thr = 16 waves = 16 heads of one (b,pair); each wave does
// qt2 = pair then 15-pair -> uniform 17 k-block iterations. Head-mean via
// LDS atomics + one plain store. Grid = 256 = 1 block/CU.
// ---------------------------------------------------------------------------
__global__ __launch_bounds__(1024) void attn_mfma(
    const __bf16* __restrict__ Q, const __bf16* __restrict__ K,
    const __bf16* __restrict__ Vt, float* __restrict__ attn_vec,
    float* __restrict__ mav)
{
    __shared__ __align__(16) __bf16 sV[64][520];   // 66.6 KB, +8 pad: 8 start banks for b128 reads
    __shared__ float smav[64][65];                 // 16.6 KB head-mean accumulator

    const int wave = threadIdx.x >> 6;     // = head
    const int lane = threadIdx.x & 63;
    const int pair = blockIdx.x & 7;
    const int b    = blockIdx.x >> 3;
    const int bh   = b * NH + wave;
    const int quad = lane >> 4;
    const int l16  = lane & 15;

    // zero the LDS head-mean accumulator
    {
        float* p = &smav[0][0];
        for (int i = threadIdx.x; i < 64 * 65; i += 1024) p[i] = 0.f;
    }

    // async-stage V into LDS: wave w stages rows w, w+16, w+32, w+48.
    // One row = 512 bf16 = 1024 B = exactly 64 lanes x 16 B (linear dest ok).
    const __bf16* Vb = Vt + (size_t)b * DH * TT;
    #pragma unroll
    for (int r = 0; r < 4; ++r) {
        const int row = wave + r * 16;
        gld16(Vb + (size_t)row * TT + lane * 8, &sV[row][0]);
    }

    const __bf16* Qbh = Q + (size_t)bh * TT * DH;
    const __bf16* Kbh = K + (size_t)bh * TT * DH;

    // permuted K row: sigma1(l16) = (l16>>2)*8 + (l16&3); sigma2 = +4
    const int perm = ((l16 >> 2) << 3) + (l16 & 3);
    const __bf16* kp1 = Kbh + (size_t)perm * DH;
    const __bf16* kp2 = Kbh + (size_t)(perm + 4) * DH;

    __syncthreads();   // V staged (compiler drains vmcnt before s_barrier)

    #pragma unroll 1
    for (int rep = 0; rep < 2; ++rep) {
        const int qt2 = rep ? (15 - pair) : pair;
        const int q0  = qt2 << 5;
        const int kend = q0 + 32;

        const bf16x8 qA_lo = *(const bf16x8*)(Qbh + (size_t)(q0 + l16) * DH + quad * 8);
        const bf16x8 qA_hi = *(const bf16x8*)(Qbh + (size_t)(q0 + l16) * DH + 32 + quad * 8);
        const bf16x8 qB_lo = *(const bf16x8*)(Qbh + (size_t)(q0 + 16 + l16) * DH + quad * 8);
        const bf16x8 qB_hi = *(const bf16x8*)(Qbh + (size_t)(q0 + 16 + l16) * DH + 32 + quad * 8);

        f32x4 OA[4] = {f32x4{0,0,0,0}, f32x4{0,0,0,0}, f32x4{0,0,0,0}, f32x4{0,0,0,0}};
        f32x4 OB[4] = {f32x4{0,0,0,0}, f32x4{0,0,0,0}, f32x4{0,0,0,0}, f32x4{0,0,0,0}};
        float lA = 0.f, lB = 0.f;     // per-lane partial denominators

        // 2-deep K register pipeline: cur (c*) + next (n*)
        bf16x8 c1a = *(const bf16x8*)(kp1 + quad * 8);
        bf16x8 c1b = *(const bf16x8*)(kp1 + 32 + quad * 8);
        bf16x8 c2a = *(const bf16x8*)(kp2 + quad * 8);
        bf16x8 c2b = *(const bf16x8*)(kp2 + 32 + quad * 8);
        const int kb1 = (32 < kend) ? 32 : 0;
        bf16x8 n1a = *(const bf16x8*)(kp1 + (size_t)kb1 * DH + quad * 8);
        bf16x8 n1b = *(const bf16x8*)(kp1 + (size_t)kb1 * DH + 32 + quad * 8);
        bf16x8 n2a = *(const bf16x8*)(kp2 + (size_t)kb1 * DH + quad * 8);
        bf16x8 n2b = *(const bf16x8*)(kp2 + (size_t)kb1 * DH + 32 + quad * 8);

        for (int kb0 = 0; kb0 < kend; kb0 += 32) {
            // V fragments from LDS (conflict-free: 8 start banks x 4-dword runs)
            const int vcol = kb0 + quad * 8;
            bf16x8 vf0 = *(const bf16x8*)&sV[l16][vcol];
            bf16x8 vf1 = *(const bf16x8*)&sV[16 + l16][vcol];
            bf16x8 vf2 = *(const bf16x8*)&sV[32 + l16][vcol];
            bf16x8 vf3 = *(const bf16x8*)&sV[48 + l16][vcol];

            f32x4 s1A = __builtin_amdgcn_mfma_f32_16x16x32_bf16(c1a, qA_lo, f32x4{0,0,0,0}, 0, 0, 0);
            s1A       = __builtin_amdgcn_mfma_f32_16x16x32_bf16(c1b, qA_hi, s1A, 0, 0, 0);
            f32x4 s2A = __builtin_amdgcn_mfma_f32_16x16x32_bf16(c2a, qA_lo, f32x4{0,0,0,0}, 0, 0, 0);
            s2A       = __builtin_amdgcn_mfma_f32_16x16x32_bf16(c2b, qA_hi, s2A, 0, 0, 0);
            f32x4 s1B = __builtin_amdgcn_mfma_f32_16x16x32_bf16(c1a, qB_lo, f32x4{0,0,0,0}, 0, 0, 0);
            s1B       = __builtin_amdgcn_mfma_f32_16x16x32_bf16(c1b, qB_hi, s1B, 0, 0, 0);
            f32x4 s2B = __builtin_amdgcn_mfma_f32_16x16x32_bf16(c2a, qB_lo, f32x4{0,0,0,0}, 0, 0, 0);
            s2B       = __builtin_amdgcn_mfma_f32_16x16x32_bf16(c2b, qB_hi, s2B, 0, 0, 0);

            if (kb0 == q0) {   // only the diagonal block needs masking
                const int qqA = q0 + l16, qqB = q0 + 16 + l16;
                #pragma unroll
                for (int r = 0; r < 4; ++r) {
                    const int key1 = kb0 + quad * 8 + r;
                    const int key2 = key1 + 4;
                    if (key1 > qqA) s1A[r] = -INFINITY;
                    if (key2 > qqA) s2A[r] = -INFINITY;
                    if (key1 > qqB) s1B[r] = -INFINITY;
                    if (key2 > qqB) s2B[r] = -INFINITY;
                }
            }

            // p = exp2(s); accumulate per-lane denominator; no rescale, no shuffles
            bf16x8 pfA, pfB;
            float psA = 0.f, psB = 0.f;
            #pragma unroll
            for (int r = 0; r < 4; ++r) {
                float pa0 = exp2f(s1A[r]);
                float pa1 = exp2f(s2A[r]);
                float pb0 = exp2f(s1B[r]);
                float pb1 = exp2f(s2B[r]);
                psA += pa0 + pa1;
                psB += pb0 + pb1;
                pfA[r]     = (__bf16)pa0;
                pfA[4 + r] = (__bf16)pa1;
                pfB[r]     = (__bf16)pb0;
                pfB[4 + r] = (__bf16)pb1;
            }
            lA += psA;
            lB += psB;

            OA[0] = __builtin_amdgcn_mfma_f32_16x16x32_bf16(pfA, vf0, OA[0], 0, 0, 0);
            OB[0] = __builtin_amdgcn_mfma_f32_16x16x32_bf16(pfB, vf0, OB[0], 0, 0, 0);
            OA[1] = __builtin_amdgcn_mfma_f32_16x16x32_bf16(pfA, vf1, OA[1], 0, 0, 0);
            OB[1] = __builtin_amdgcn_mfma_f32_16x16x32_bf16(pfB, vf1, OB[1], 0, 0, 0);
            OA[2] = __builtin_amdgcn_mfma_f32_16x16x32_bf16(pfA, vf2, OA[2], 0, 0, 0);
            OB[2] = __builtin_amdgcn_mfma_f32_16x16x32_bf16(pfB, vf2, OB[2], 0, 0, 0);
            OA[3] = __builtin_amdgcn_mfma_f32_16x16x32_bf16(pfA, vf3, OA[3], 0, 0, 0);
            OB[3] = __builtin_amdgcn_mfma_f32_16x16x32_bf16(pfB, vf3, OB[3], 0, 0, 0);

            // rotate K pipeline: cur <- next, issue next-next (clamped).
            // Placed after PV so the pending n* loads get the whole iteration
            // to land before the copy's waitcnt.
            c1a = n1a; c1b = n1b; c2a = n2a; c2b = n2b;
            const int kbn = (kb0 + 64 < kend) ? kb0 + 64 : kend - 32;
            const __bf16* nk1 = kp1 + (size_t)kbn * DH;
            const __bf16* nk2 = kp2 + (size_t)kbn * DH;
            n1a = *(const bf16x8*)(nk1 + quad * 8);
            n1b = *(const bf16x8*)(nk1 + 32 + quad * 8);
            n2a = *(const bf16x8*)(nk2 + quad * 8);
            n2b = *(const bf16x8*)(nk2 + 32 + quad * 8);
        }

        // reduce denominators across quads (each lane then holds the full sum
        // for query l16 (A) / 16+l16 (B))
        lA += __shfl_xor(lA, 16);
        lA += __shfl_xor(lA, 32);
        lB += __shfl_xor(lB, 16);
        lB += __shfl_xor(lB, 32);

        #pragma unroll
        for (int r = 0; r < 4; ++r) {
            const float invA = 1.0f / __shfl(lA, quad * 4 + r);
            const float invB = 1.0f / __shfl(lB, quad * 4 + r);
            const int tA = q0 + quad * 4 + r;
            const int tB = tA + 16;
            const int ltA = rep * 32 + quad * 4 + r;   // LDS row (tile-local + rep offset)
            const int ltB = ltA + 16;
            float* opA = attn_vec + ((size_t)bh * TT + tA) * DH + l16;
            float* opB = attn_vec + ((size_t)bh * TT + tB) * DH + l16;
            #pragma unroll
            for (int nt = 0; nt < 4; ++nt) {
                const float vA = OA[nt][r] * invA;
                const float vB = OB[nt][r] * invB;
                opA[nt * 16] = vA;
                opB[nt * 16] = vB;
                atomicAdd(&smav[ltA][nt * 16 + l16], vA * (1.f / 16.f));
                atomicAdd(&smav[ltB][nt * 16 + l16], vB * (1.f / 16.f));
            }
        }
    }

    __syncthreads();

    // block-cooperative plain store of the head-mean (each element written once)
    {
        const int row = threadIdx.x >> 4;          // 0..63
        const int d0  = (threadIdx.x & 15) * 4;
        const int t   = (row < 32) ? ((pair << 5) + row)
                                   : (((15 - pair) << 5) + (row - 32));
        float4 v;
        v.x = smav[row][d0];
        v.y = smav[row][d0 + 1];
        v.z = smav[row][d0 + 2];
        v.w = smav[row][d0 + 3];
        *(float4*)(mav + ((size_t)(b * TT + t)) * DH + d0) = v;
    }
}

// ---------------------------------------------------------------------------
// Out-proj GEMM (64x64 tile, fp32 A): out[M,1024] = mav[M,64] @ Wo[64,1024]
// ---------------------------------------------------------------------------
__global__ __launch_bounds__(256) void gemm_out(
    const float* __restrict__ A, const float* __restrict__ B,
    float* __restrict__ C, int M, int N, int K)
{
    __shared__ __align__(16) __bf16 sA[64][32];
    __shared__ __align__(16) __bf16 sB[64][32];

    const int tid  = threadIdx.x;
    const int wave = tid >> 6;
    const int lane = tid & 63;
    const int m0 = blockIdx.y * 64;
    const int n0 = blockIdx.x * 64;

    f32x4 acc[4] = {f32x4{0,0,0,0}, f32x4{0,0,0,0}, f32x4{0,0,0,0}, f32x4{0,0,0,0}};

    const int ar = tid >> 2;
    const int ac = (tid & 3) * 8;
    const int bk = tid >> 3;
    const int bc = (tid & 7) * 8;
    const int quad = lane >> 4;
    const int l16  = lane & 15;

    for (int k0 = 0; k0 < K; k0 += 32) {
        const float* ap = A + (size_t)(m0 + ar) * K + k0 + ac;
        float4 a0 = *(const float4*)ap;
        float4 a1 = *(const float4*)(ap + 4);
        {
            bf16x8 av;
            av[0] = (__bf16)a0.x; av[1] = (__bf16)a0.y; av[2] = (__bf16)a0.z; av[3] = (__bf16)a0.w;
            av[4] = (__bf16)a1.x; av[5] = (__bf16)a1.y; av[6] = (__bf16)a1.z; av[7] = (__bf16)a1.w;
            *(bf16x8*)&sA[ar][ac] = av;
        }
        const float* bp = B + (size_t)(k0 + bk) * N + n0 + bc;
        float4 b0 = *(const float4*)bp;
        float4 b1 = *(const float4*)(bp + 4);
        sB[bc + 0][bk] = (__bf16)b0.x;
        sB[bc + 1][bk] = (__bf16)b0.y;
        sB[bc + 2][bk] = (__bf16)b0.z;
        sB[bc + 3][bk] = (__bf16)b0.w;
        sB[bc + 4][bk] = (__bf16)b1.x;
        sB[bc + 5][bk] = (__bf16)b1.y;
        sB[bc + 6][bk] = (__bf16)b1.z;
        sB[bc + 7][bk] = (__bf16)b1.w;
        __syncthreads();

        bf16x8 afrag = *(const bf16x8*)&sA[wave * 16 + l16][quad * 8];
        #pragma unroll
        for (int tn = 0; tn < 4; ++tn) {
            bf16x8 bfrag = *(const bf16x8*)&sB[tn * 16 + l16][quad * 8];
            acc[tn] = __builtin_amdgcn_mfma_f32_16x16x32_bf16(afrag, bfrag, acc[tn], 0, 0, 0);
        }
        __syncthreads();
    }

    #pragma unroll
    for (int tn = 0; tn < 4; ++tn) {
        #pragma unroll
        for (int r = 0; r < 4; ++r) {
            int row = m0 + wave * 16 + quad * 4 + r;
            int col = n0 + tn * 16 + l16;
            C[(size_t)row * N + col] = acc[tn][r];
        }
    }
}

// ---------------------------------------------------------------------------
extern "C" void kernel_launch(void* const* d_in, const int* in_sizes, int n_in,
                              void* d_out, int out_size, void* d_ws, size_t ws_size,
                              hipStream_t stream)
{
    const float* x  = (const float*)d_in[0];
    const float* Wq = (const float*)d_in[1];
    const float* bq = (const float*)d_in[2];
    const float* Wk = (const float*)d_in[3];
    const float* bk = (const float*)d_in[4];
    const float* Wv = (const float*)d_in[5];
    const float* bv = (const float*)d_in[6];
    const float* Wo = (const float*)d_in[7];

    float* out      = (float*)d_out;                       // [32,512,1024]
    float* attn_vec = out + (size_t)MM * HH;               // [32,16,512,64]

    char* ws = (char*)d_ws;
    __bf16* xb  = (__bf16*)ws;                              // [M][1024]    33.5 MB
    __bf16* Wt  = xb + (size_t)MM * HH;                     // [2176][1024]  4.45 MB
    float* bias_cat = (float*)(Wt + (size_t)NCAT * HH);     // 2176 (pad 2304)
    __bf16* Qb  = (__bf16*)(bias_cat + 2304);               // [b,h,t,d]    33.5 MB
    __bf16* Kb  = Qb + (size_t)MM * HH;                     // [b,h,t,d]    33.5 MB
    __bf16* Vt  = Kb + (size_t)MM * HH;                     // [b,d,t]       2.1 MB
    float*  mav = (float*)xb;   // alias: xb dead after gemm_qkv; fully overwritten by attn

    cvt_x<<<MM * HH / (256 * 8), 256, 0, stream>>>(x, xb);
    prep_w<<<dim3(NCAT / 64, HH / 64), 256, 0, stream>>>(Wq, Wk, Wv, bq, bk, bv, Wt, bias_cat);
    gemm_qkv<<<dim3(NCAT / 128, MM / 128), 256, 0, stream>>>(xb, Wt, bias_cat, Qb, Kb, Vt);
    attn_mfma<<<BS * 8, 1024, 0, stream>>>(Qb, Kb, Vt, attn_vec, mav);
    gemm_out<<<dim3(HH / 64, MM / 64), 256, 0, stream>>>(mav, Wo, out, MM, HH, DH);
}